// Round 7
// baseline (1035.032 us; speedup 1.0000x reference)
//
#include <hip/hip_runtime.h>

#define KF 128
#define NSUP 256
#define NSPEC 4
#define GRID 256
#define BLOCK 1024   // 16 waves; G (128 KB) in LDS -> 1 block/CU

typedef __bf16 bf16x8 __attribute__((ext_vector_type(8)));
typedef float  f32x4  __attribute__((ext_vector_type(4)));

// ---------------- build per-species Gram matrix ----------------
// G[s][c][k] = sum_m w[s][m] * sup[s][m][c] * sup[s][m][k]   (bf16 out, fp32 accum)

__global__ void k_buildG(const float* __restrict__ sup, const float* __restrict__ w,
                         __bf16* __restrict__ Gout) {
    const int s = blockIdx.x >> 7;
    const int c = blockIdx.x & 127;
    const int k = threadIdx.x;
    const float* S = sup + (size_t)s * NSUP * KF;
    const float* W = w + s * NSUP;
    float acc = 0.f;
    #pragma unroll 4
    for (int m = 0; m < NSUP; ++m)
        acc += W[m] * S[m * KF + c] * S[m * KF + k];
    Gout[((size_t)(s * 128 + c)) * 128 + k] = (__bf16)acc;
}

// ---------------- helpers (register-only, no arrays) ----------------

__device__ __forceinline__ int4 cvt8(const float* p, bool v, float& nacc) {
    float4 A = v ? *(const float4*)p : make_float4(0.f, 0.f, 0.f, 0.f);
    float4 B = v ? *(const float4*)(p + 4) : make_float4(0.f, 0.f, 0.f, 0.f);
    nacc += A.x * A.x + A.y * A.y + A.z * A.z + A.w * A.w
          + B.x * B.x + B.y * B.y + B.z * B.z + B.w * B.w;
    bf16x8 o;
    o[0] = (__bf16)A.x; o[1] = (__bf16)A.y; o[2] = (__bf16)A.z; o[3] = (__bf16)A.w;
    o[4] = (__bf16)B.x; o[5] = (__bf16)B.y; o[6] = (__bf16)B.z; o[7] = (__bf16)B.w;
    return __builtin_bit_cast(int4, o);
}

// One ct-step: extract x (C-layout) via 4-lane shuffle, then 4 species x 4 kk MFMA
// for both atom-sets, fused species-predicated pairing into eA/eB.
template<int CT>
__device__ __forceinline__ void ct_step(
    int4 fA0, int4 fA1, int4 fA2, int4 fA3,
    int4 fB0, int4 fB1, int4 fB2, int4 fB3,
    const char* Glds, int r, int g, int swz,
    int spcA, int spcB, float& eA, float& eB)
{
    constexpr int KP = CT >> 1;
    const int4 sA = (KP == 0) ? fA0 : (KP == 1) ? fA1 : (KP == 2) ? fA2 : fA3;
    const int4 sB = (KP == 0) ? fB0 : (KP == 1) ? fB1 : (KP == 2) ? fB2 : fB3;

    const int srcl = (((CT & 1) * 2 + (g >> 1)) << 4) | r;
    int a0 = __shfl(sA.x, srcl), a1 = __shfl(sA.y, srcl),
        a2 = __shfl(sA.z, srcl), a3 = __shfl(sA.w, srcl);
    int b0 = __shfl(sB.x, srcl), b1 = __shfl(sB.y, srcl),
        b2 = __shfl(sB.z, srcl), b3 = __shfl(sB.w, srcl);
    const int loA = (g & 1) ? a2 : a0, hiA = (g & 1) ? a3 : a1;
    const int loB = (g & 1) ? b2 : b0, hiB = (g & 1) ? b3 : b1;
    const float xa0 = __int_as_float(loA << 16);
    const float xa1 = __int_as_float(loA & 0xffff0000);
    const float xa2 = __int_as_float(hiA << 16);
    const float xa3 = __int_as_float(hiA & 0xffff0000);
    const float xb0 = __int_as_float(loB << 16);
    const float xb1 = __int_as_float(loB & 0xffff0000);
    const float xb2 = __int_as_float(hiB << 16);
    const float xb3 = __int_as_float(hiB & 0xffff0000);

    const int abase = ((CT * 16 + r) << 8) + (g << 4);

    #pragma unroll
    for (int s = 0; s < NSPEC; ++s) {
        f32x4 aA = (f32x4){0.f, 0.f, 0.f, 0.f};
        f32x4 aB = (f32x4){0.f, 0.f, 0.f, 0.f};
        {
            bf16x8 Gf = *(const bf16x8*)(Glds + ((((s << 15) | (abase + 0)) ) ^ swz));
            aA = __builtin_amdgcn_mfma_f32_16x16x32_bf16(Gf, __builtin_bit_cast(bf16x8, fA0), aA, 0, 0, 0);
            aB = __builtin_amdgcn_mfma_f32_16x16x32_bf16(Gf, __builtin_bit_cast(bf16x8, fB0), aB, 0, 0, 0);
        }
        {
            bf16x8 Gf = *(const bf16x8*)(Glds + ((((s << 15) | (abase + 64)) ) ^ swz));
            aA = __builtin_amdgcn_mfma_f32_16x16x32_bf16(Gf, __builtin_bit_cast(bf16x8, fA1), aA, 0, 0, 0);
            aB = __builtin_amdgcn_mfma_f32_16x16x32_bf16(Gf, __builtin_bit_cast(bf16x8, fB1), aB, 0, 0, 0);
        }
        {
            bf16x8 Gf = *(const bf16x8*)(Glds + ((((s << 15) | (abase + 128)) ) ^ swz));
            aA = __builtin_amdgcn_mfma_f32_16x16x32_bf16(Gf, __builtin_bit_cast(bf16x8, fA2), aA, 0, 0, 0);
            aB = __builtin_amdgcn_mfma_f32_16x16x32_bf16(Gf, __builtin_bit_cast(bf16x8, fB2), aB, 0, 0, 0);
        }
        {
            bf16x8 Gf = *(const bf16x8*)(Glds + ((((s << 15) | (abase + 192)) ) ^ swz));
            aA = __builtin_amdgcn_mfma_f32_16x16x32_bf16(Gf, __builtin_bit_cast(bf16x8, fA3), aA, 0, 0, 0);
            aB = __builtin_amdgcn_mfma_f32_16x16x32_bf16(Gf, __builtin_bit_cast(bf16x8, fB3), aB, 0, 0, 0);
        }
        float dA = xa0 * aA[0] + xa1 * aA[1] + xa2 * aA[2] + xa3 * aA[3];
        float dB = xb0 * aB[0] + xb1 * aB[1] + xb2 * aB[2] + xb3 * aB[3];
        if (spcA == s) eA += dA;
        if (spcB == s) eB += dB;
    }
}

// ---------------- main kernel: sequential stream, Gram form ----------------

__global__ __launch_bounds__(BLOCK, 1) void k_main(
    const float* __restrict__ ps,
    const __bf16* __restrict__ Gws,
    const int* __restrict__ species,
    const int* __restrict__ sids,
    float* __restrict__ out,
    int n)
{
    __shared__ __align__(16) char Glds[NSPEC * 128 * 256];   // 128 KB

    // stage G -> LDS, XOR-swizzled: byte ^= ((row&7)<<4), row = byte>>8
    for (int f = threadIdx.x; f < 8192; f += BLOCK) {
        int4 v = ((const int4*)Gws)[f];
        int dst = (f * 16) ^ (((f >> 4) & 7) << 4);
        *(int4*)(Glds + dst) = v;
    }
    __syncthreads();

    const int lane = threadIdx.x & 63;
    const int r = lane & 15, g = lane >> 4;
    const int swz = (r & 7) << 4;
    const int wid = blockIdx.x * (BLOCK / 64) + (threadIdx.x >> 6);
    const int gs = GRID * (BLOCK / 64);
    const int ntiles = (n + 31) / 32;

    for (int t = wid; t < ntiles; t += gs) {
        const int base = t * 32;

        // ---- load both 16-atom sets: meta + fragments + norms ----
        int aA = base + r,      aB = base + 16 + r;
        bool vA = aA < n,       vB = aB < n;
        int rA = vA ? aA : 0,   rB = vB ? aB : 0;
        int spcA = vA ? species[rA] : -1;
        int spcB = vB ? species[rB] : -1;
        int sidA = vA ? sids[rA] : 0;
        int sidB = vB ? sids[rB] : 0;

        const float* pA = ps + (size_t)rA * KF + g * 8;
        const float* pB = ps + (size_t)rB * KF + g * 8;
        float nA = 0.f, nB = 0.f;
        int4 fA0 = cvt8(pA +  0, vA, nA);
        int4 fA1 = cvt8(pA + 32, vA, nA);
        int4 fA2 = cvt8(pA + 64, vA, nA);
        int4 fA3 = cvt8(pA + 96, vA, nA);
        int4 fB0 = cvt8(pB +  0, vB, nB);
        int4 fB1 = cvt8(pB + 32, vB, nB);
        int4 fB2 = cvt8(pB + 64, vB, nB);
        int4 fB3 = cvt8(pB + 96, vB, nB);
        nA += __shfl_xor(nA, 16); nA += __shfl_xor(nA, 32);
        nB += __shfl_xor(nB, 16); nB += __shfl_xor(nB, 32);

        // ---- compute: 8 ct-steps ----
        float eA = 0.f, eB = 0.f;
        ct_step<0>(fA0,fA1,fA2,fA3, fB0,fB1,fB2,fB3, Glds, r, g, swz, spcA, spcB, eA, eB);
        ct_step<1>(fA0,fA1,fA2,fA3, fB0,fB1,fB2,fB3, Glds, r, g, swz, spcA, spcB, eA, eB);
        ct_step<2>(fA0,fA1,fA2,fA3, fB0,fB1,fB2,fB3, Glds, r, g, swz, spcA, spcB, eA, eB);
        ct_step<3>(fA0,fA1,fA2,fA3, fB0,fB1,fB2,fB3, Glds, r, g, swz, spcA, spcB, eA, eB);
        ct_step<4>(fA0,fA1,fA2,fA3, fB0,fB1,fB2,fB3, Glds, r, g, swz, spcA, spcB, eA, eB);
        ct_step<5>(fA0,fA1,fA2,fA3, fB0,fB1,fB2,fB3, Glds, r, g, swz, spcA, spcB, eA, eB);
        ct_step<6>(fA0,fA1,fA2,fA3, fB0,fB1,fB2,fB3, Glds, r, g, swz, spcA, spcB, eA, eB);
        ct_step<7>(fA0,fA1,fA2,fA3, fB0,fB1,fB2,fB3, Glds, r, g, swz, spcA, spcB, eA, eB);

        // ---- per-lane energies (g-slice partials) ----
        float uA = (nA > 0.f) ? eA / nA : 0.f;
        float uB = (nB > 0.f) ? eB / nB : 0.f;

        // ---- emit: uniform-sid fast path (sids sorted -> common) ----
        int s0 = __shfl(sidA, 0);
        bool uni = __all(sidA == s0) && __all(sidB == s0);
        if (uni) {
            float tot = uA + uB;
            tot += __shfl_xor(tot, 1);  tot += __shfl_xor(tot, 2);
            tot += __shfl_xor(tot, 4);  tot += __shfl_xor(tot, 8);
            tot += __shfl_xor(tot, 16); tot += __shfl_xor(tot, 32);
            if (lane == 0 && tot != 0.f) atomicAdd(&out[s0], tot);
        } else {
            uA += __shfl_xor(uA, 16); uA += __shfl_xor(uA, 32);
            uB += __shfl_xor(uB, 16); uB += __shfl_xor(uB, 32);
            if (g == 0) {
                if (vA) atomicAdd(&out[sidA], uA);
                if (vB) atomicAdd(&out[sidB], uB);
            }
        }
    }
}

// ---------------- slow-but-correct fallback (ws too small) ----------------

__global__ void k_fallback(const float* __restrict__ ps, const float* __restrict__ support,
                           const float* __restrict__ weights, const int* __restrict__ species,
                           const int* __restrict__ struct_ids, float* __restrict__ out, int n)
{
    int gw = (blockIdx.x * blockDim.x + threadIdx.x) >> 6;
    int lane = threadIdx.x & 63;
    int nw = (gridDim.x * blockDim.x) >> 6;
    for (int atom = gw; atom < n; atom += nw) {
        const float* row = ps + (size_t)atom * KF;
        float x0 = row[lane], x1 = row[lane + 64];
        float nsum = x0 * x0 + x1 * x1;
        for (int o = 32; o; o >>= 1) nsum += __shfl_xor(nsum, o);
        float iv2 = 1.0f / nsum;
        int s = species[atom];
        const float* sup = support + (size_t)s * NSUP * KF;
        const float* w = weights + (size_t)s * NSUP;
        float e = 0.f;
        for (int mm = 0; mm < 4; ++mm) {
            int m = lane + mm * 64;
            const float* srow = sup + (size_t)m * KF;
            float d = 0.f;
            for (int k = 0; k < KF; ++k) d += row[k] * srow[k];
            e += d * d * w[m];
        }
        for (int o = 32; o; o >>= 1) e += __shfl_xor(e, o);
        if (lane == 0) atomicAdd(&out[struct_ids[atom]], e * iv2);
    }
}

// ---------------- launch ----------------

extern "C" void kernel_launch(void* const* d_in, const int* in_sizes, int n_in,
                              void* d_out, int out_size, void* d_ws, size_t ws_size,
                              hipStream_t stream)
{
    const float* ps       = (const float*)d_in[0];
    const float* support  = (const float*)d_in[1];
    const float* weights  = (const float*)d_in[2];
    const int*   species  = (const int*)d_in[3];
    const int*   sids     = (const int*)d_in[4];
    float* out = (float*)d_out;
    const int n = in_sizes[0] / KF;

    hipMemsetAsync(d_out, 0, (size_t)out_size * sizeof(float), stream);

    const size_t gbytes = (size_t)NSPEC * 128 * 128 * sizeof(__bf16);   // 128 KB
    if (ws_size < gbytes) {
        k_fallback<<<2048, 256, 0, stream>>>(ps, support, weights, species, sids, out, n);
        return;
    }

    __bf16* Gws = (__bf16*)d_ws;
    k_buildG<<<NSPEC * 128, 128, 0, stream>>>(support, weights, Gws);
    k_main<<<GRID, BLOCK, 0, stream>>>(ps, Gws, species, sids, out, n);
}